// Round 17
// baseline (152.315 us; speedup 1.0000x reference)
//
#include <hip/hip_runtime.h>
#include <hip/hip_bf16.h>
#include <cstdint>

#define D_MODEL 1024
#define SEQ     2048
#define SCALE   0.125f
#define P_ELEMS 2228224   // per-batch packed triangular elems: 16384*136

typedef __attribute__((ext_vector_type(8))) _Float16 f16x8;
typedef __attribute__((ext_vector_type(8))) unsigned short u16x8;
typedef __attribute__((ext_vector_type(4))) float f32x4;

__device__ __forceinline__ unsigned short f2h(float f) {
  _Float16 h = (_Float16)f;
  return __builtin_bit_cast(unsigned short, h);
}
__device__ __forceinline__ float h2f(unsigned short u) {
  return (float)__builtin_bit_cast(_Float16, u);
}

__device__ __forceinline__ void gll16(const void* g, void* lds_p) {
  __builtin_amdgcn_global_load_lds(
      (const __attribute__((address_space(1))) unsigned int*)(uintptr_t)g,
      (__attribute__((address_space(3))) unsigned int*)(unsigned int)(uintptr_t)lds_p,
      16, 0, 0);
}

#define WAITV8 asm volatile("s_waitcnt vmcnt(8)" ::: "memory")
#define WAITV0 asm volatile("s_waitcnt vmcnt(0)" ::: "memory")
#define WAITL8 asm volatile("s_waitcnt lgkmcnt(8)" ::: "memory")
#define WAITL0 asm volatile("s_waitcnt lgkmcnt(0)" ::: "memory")
#define SCHEDB __builtin_amdgcn_sched_barrier(0)
#define BAR    __builtin_amdgcn_s_barrier()
#define PRIO1  __builtin_amdgcn_s_setprio(1)
#define PRIO0  __builtin_amdgcn_s_setprio(0)
#define MFMA16(a, b, c) __builtin_amdgcn_mfma_f32_16x16x32_f16(a, b, c, 0, 0, 0)

// ============ 128-tile pipeline (4 waves), 16x16x32 core (r14-verified) ============
__device__ __forceinline__ void stage_tile(const unsigned short* gA, const unsigned short* gB,
                                           size_t sA, size_t sB,
                                           int k0, unsigned short* buf, int w, int lane) {
  int rl = lane >> 3;
  int sg = ((lane & 7) ^ rl) << 3;
#pragma unroll
  for (int j = 0; j < 4; j++) {
    int c = w * 4 + j;
    int row = c * 8 + rl;
    gll16(gA + (size_t)row * sA + k0 + sg, buf + c * 512);
    gll16(gB + (size_t)row * sB + k0 + sg, buf + 8192 + c * 512);
  }
}

__device__ __forceinline__ void gemm_core(const unsigned short* gA, const unsigned short* gB,
                                          size_t sA, size_t sB,
                                          unsigned short* lds0, unsigned short* lds1, int nt,
                                          int w, int lane, int wr, int wc, int l15, int l4,
                                          f32x4 acc[4][4]) {
  stage_tile(gA, gB, sA, sB, 0, lds0, w, lane);
  stage_tile(gA, gB, sA, sB, 64, lds1, w, lane);
  WAITV8; SCHEDB; BAR;
  for (int t = 0; t < nt; t++) {
    const unsigned short* buf = (t & 1) ? lds1 : lds0;
    const unsigned short* bA = buf;
    const unsigned short* bB = buf + 8192;
    f16x8 a0[4], b0[4], a1[4], b1[4];
#pragma unroll
    for (int m = 0; m < 4; m++) {
      int row = wr * 64 + m * 16 + l15, rs = row & 7;
      a0[m] = *(const f16x8*)(bA + row * 64 + ((l4 ^ rs) << 3));
    }
#pragma unroll
    for (int n = 0; n < 4; n++) {
      int row = wc * 64 + n * 16 + l15, rs = row & 7;
      b0[n] = *(const f16x8*)(bB + row * 64 + ((l4 ^ rs) << 3));
    }
#pragma unroll
    for (int m = 0; m < 4; m++) {
      int row = wr * 64 + m * 16 + l15, rs = row & 7;
      a1[m] = *(const f16x8*)(bA + row * 64 + (((4 + l4) ^ rs) << 3));
    }
#pragma unroll
    for (int n = 0; n < 4; n++) {
      int row = wc * 64 + n * 16 + l15, rs = row & 7;
      b1[n] = *(const f16x8*)(bB + row * 64 + (((4 + l4) ^ rs) << 3));
    }
    WAITL8; SCHEDB;
    PRIO1;
#pragma unroll
    for (int m = 0; m < 4; m++)
#pragma unroll
      for (int n = 0; n < 4; n++)
        acc[m][n] = MFMA16(a0[m], b0[n], acc[m][n]);
    PRIO0;
    WAITL0; SCHEDB; BAR;
    if (t + 2 < nt) stage_tile(gA, gB, sA, sB, (t + 2) * 64,
                               (unsigned short*)buf, w, lane);
    PRIO1;
#pragma unroll
    for (int m = 0; m < 4; m++)
#pragma unroll
      for (int n = 0; n < 4; n++)
        acc[m][n] = MFMA16(a1[m], b1[n], acc[m][n]);
    PRIO0;
    if (t + 2 < nt) { WAITV8; } else { WAITV0; }
    SCHEDB; BAR;
  }
}

// ---- kernel 1: fused converts ----
__global__ __launch_bounds__(256) void cvt_fused(const float* __restrict__ x,
                                                 const float* __restrict__ W0,
                                                 const float* __restrict__ W1,
                                                 const float* __restrict__ W2,
                                                 unsigned short* __restrict__ xb,
                                                 unsigned short* __restrict__ wt) {
  __shared__ float t[32][33];
  int bid = blockIdx.x;
  int tid = threadIdx.x;
  if (bid < 4096) {
    int i = bid * 256 + tid;
    const float4* p = (const float4*)x + (size_t)i * 2;
    float4 a = p[0], b = p[1];
    u16x8 r;
    r[0] = f2h(a.x); r[1] = f2h(a.y); r[2] = f2h(a.z); r[3] = f2h(a.w);
    r[4] = f2h(b.x); r[5] = f2h(b.y); r[6] = f2h(b.z); r[7] = f2h(b.w);
    *((u16x8*)xb + i) = r;
  } else {
    int id = bid - 4096;
    int z = id >> 10, rem = id & 1023;
    int bx = rem & 31, by = rem >> 5;
    const float* W = (z == 0) ? W0 : (z == 1 ? W1 : W2);
    unsigned short* o = wt + (size_t)z * 1048576;
    int c0 = bx * 32, r0 = by * 32;
    int tx = tid & 31, ty = tid >> 5;
    for (int i = 0; i < 4; i++)
      t[ty + 8 * i][tx] = W[(size_t)(r0 + ty + 8 * i) * 1024 + c0 + tx];
    __syncthreads();
    for (int i = 0; i < 4; i++)
      o[(size_t)(c0 + ty + 8 * i) * 1024 + r0 + tx] = f2h(t[tx][ty + 8 * i]);
  }
}

// ---- kernel 2: QK GEMM only (1024 blocks = 2 exact rounds); LDS-bounce epilogue ----
__global__ __launch_bounds__(256) void qkv_gemm(const unsigned short* __restrict__ xb,
                                                const unsigned short* __restrict__ wt,
                                                const float* __restrict__ b0,
                                                const float* __restrict__ b1,
                                                unsigned short* __restrict__ Qp,
                                                unsigned short* __restrict__ Kp) {
  __shared__ unsigned short lds[2][16384];
  int m0 = blockIdx.x * 128;
  int n0 = blockIdx.y * 128;
  int z = n0 >> 10, nz = n0 & 1023;
  const unsigned short* gA = xb + (size_t)m0 * 1024;
  const unsigned short* gB = wt + (size_t)z * 1048576 + (size_t)nz * 1024;
  const float* bias = z ? b1 : b0;
  unsigned short* O = z ? Kp : Qp;
  int tid = threadIdx.x, lane = tid & 63, w = tid >> 6;
  int wr = w >> 1, wc = w & 1, l15 = lane & 15, l4 = lane >> 4;
  f32x4 acc[4][4] = {};
  gemm_core(gA, gB, 1024, 1024, &lds[0][0], &lds[1][0], 16, w, lane, wr, wc, l15, l4, acc);

  unsigned short* T = &lds[0][0];            // 128 x 136 f16 bounce
#pragma unroll
  for (int m = 0; m < 4; m++)
#pragma unroll
    for (int n = 0; n < 4; n++) {
      int cl = wc * 64 + n * 16 + l15;
      float bv = bias[nz + cl];
#pragma unroll
      for (int r = 0; r < 4; r++) {
        int rl = wr * 64 + m * 16 + l4 * 4 + r;
        T[rl * 136 + cl] = f2h(acc[m][n][r] + bv);
      }
    }
  __syncthreads();
#pragma unroll
  for (int i = 0; i < 8; i++) {
    int idx = i * 256 + tid;
    int row = idx >> 4, ch = idx & 15;
    u16x8 v = *(const u16x8*)(T + row * 136 + ch * 8);
    *(u16x8*)(O + (size_t)(m0 + row) * 1024 + nz + ch * 8) = v;
  }
}

// ---- kernel 3: fused scores + V, unit-balanced 992-block grid ----
// ids 0-31: score doubles | 32-63: paired singles (tiles 416..479)
// ids 64-575: 512 V blocks | 576-991: 416 remaining singles (tiles 0..415)
__global__ __launch_bounds__(256) void scores_v(const unsigned short* __restrict__ Q,
                                                const unsigned short* __restrict__ Kb,
                                                const unsigned short* __restrict__ xb,
                                                const unsigned short* __restrict__ wt,
                                                const float* __restrict__ bvf,
                                                unsigned short* __restrict__ sc,
                                                unsigned short* __restrict__ vtp) {
  __shared__ unsigned short lds[2][16384];
  int blk = blockIdx.x;
  int tid = threadIdx.x, lane = tid & 63, w = tid >> 6;
  int wr = w >> 1, wc = w & 1, l15 = lane & 15, l4 = lane >> 4;
  if (blk < 64 || blk >= 576) {
    int t0, t1, ntile;
    if (blk < 32)      { t0 = 480 + blk;             t1 = 512 + blk;  ntile = 2; }
    else if (blk < 64) { int p = blk - 32; t0 = 416 + 2 * p; t1 = t0 + 1; ntile = 2; }
    else               { t0 = blk - 576;             t1 = 0;          ntile = 1; }
    for (int u = 0; u < ntile; u++) {
      int ti = (u == 0) ? t0 : t1;
      int b = ti / 136, i = ti % 136;
      int qt = (int)((sqrtf(8.f * i + 1.f) - 1.f) * 0.5f);
      while ((qt + 1) * (qt + 2) / 2 <= i) qt++;
      while (qt * (qt + 1) / 2 > i) qt--;
      int kt = i - qt * (qt + 1) / 2;
      int Wspan = (qt + 1) << 7;
      const unsigned short* gA = Q  + ((size_t)b * 2048 + qt * 128) * 1024;
      const unsigned short* gB = Kb + ((size_t)b * 2048 + kt * 128) * 1024;
      unsigned short* outp = sc + (size_t)b * P_ELEMS + (size_t)16384 * (qt * (qt + 1) / 2);
      f32x4 acc[4][4] = {};
      gemm_core(gA, gB, 1024, 1024, &lds[0][0], &lds[1][0], 16, w, lane, wr, wc, l15, l4, acc);
      unsigned short* T = &lds[0][0];
#pragma unroll
      for (int m = 0; m < 4; m++)
#pragma unroll
        for (int n = 0; n < 4; n++) {
          int cl = wc * 64 + n * 16 + l15;
          int kv = kt * 128 + cl;
#pragma unroll
          for (int r = 0; r < 4; r++) {
            int rl = wr * 64 + m * 16 + l4 * 4 + r;
            int srow = qt * 128 + rl;
            float v = acc[m][n][r] * SCALE;
            if (kv > srow) v = -30000.f;
            T[rl * 136 + cl] = f2h(v);
          }
        }
      __syncthreads();
#pragma unroll
      for (int i2 = 0; i2 < 8; i2++) {
        int idx = i2 * 256 + tid;
        int row = idx >> 4, ch = idx & 15;
        u16x8 v = *(const u16x8*)(T + row * 136 + ch * 8);
        *(u16x8*)(outp + (size_t)row * Wspan + kt * 128 + ch * 8) = v;
      }
      __syncthreads();
    }
  } else {
    int id = blk - 64;                        // 0..511
    int m0 = (id & 63) * 128;
    int n0v = (id >> 6) * 128;                // 0..896
    const unsigned short* gA = xb + (size_t)m0 * 1024;
    const unsigned short* gB = wt + (size_t)2 * 1048576 + (size_t)n0v * 1024;
    f32x4 acc[4][4] = {};
    gemm_core(gA, gB, 1024, 1024, &lds[0][0], &lds[1][0], 16, w, lane, wr, wc, l15, l4, acc);
    unsigned short* T = &lds[0][0];           // transposed bounce: T[d][s]
#pragma unroll
    for (int m = 0; m < 4; m++)
#pragma unroll
      for (int n = 0; n < 4; n++) {
        int cl = wc * 64 + n * 16 + l15;      // d-local
        float bvv = bvf[n0v + cl];
#pragma unroll
        for (int r = 0; r < 4; r++) {
          int rl = wr * 64 + m * 16 + l4 * 4 + r;    // s-local
          T[cl * 136 + rl] = f2h(acc[m][n][r] + bvv);
        }
      }
    __syncthreads();
    int bidx = m0 >> 11, s0 = m0 & 2047;
#pragma unroll
    for (int i = 0; i < 8; i++) {
      int d = w * 32 + i * 4 + (lane >> 4);
      int ch = lane & 15;
      u16x8 v = *(const u16x8*)(T + d * 136 + ch * 8);
      *(u16x8*)(vtp + ((size_t)bidx * 1024 + n0v + d) * 2048 + s0 + ch * 8) = v;
    }
  }
}

// ---- kernel 4: per-wave row softmax (4 same-width rows per block) ----
__global__ __launch_bounds__(256) void softmax_row(const unsigned short* __restrict__ sc,
                                                   unsigned short* __restrict__ pb) {
  int base = blockIdx.x * 4;
  int b = base >> 11, sl0 = base & 2047;
  int w = threadIdx.x >> 6, lane = threadIdx.x & 63;
  int sl = sl0 + w;
  int qt = sl >> 7;
  int Wspan = (qt + 1) << 7;
  size_t rb = (size_t)b * P_ELEMS + (size_t)16384 * (qt * (qt + 1) / 2) + (size_t)(sl & 127) * Wspan;
  const u16x8* src = (const u16x8*)(sc + rb);
  int nc = Wspan >> 3;
  bool h0 = lane < nc, h1 = lane + 64 < nc, h2 = lane + 128 < nc, h3 = lane + 192 < nc;
  float v0[8], v1[8], v2[8], v3[8];
  float mx = -1e30f;
  if (h0) { u16x8 r = src[lane];
#pragma unroll
    for (int j = 0; j < 8; j++) { v0[j] = h2f(r[j]); mx = fmaxf(mx, v0[j]); } }
  if (h1) { u16x8 r = src[lane + 64];
#pragma unroll
    for (int j = 0; j < 8; j++) { v1[j] = h2f(r[j]); mx = fmaxf(mx, v1[j]); } }
  if (h2) { u16x8 r = src[lane + 128];
#pragma unroll
    for (int j = 0; j < 8; j++) { v2[j] = h2f(r[j]); mx = fmaxf(mx, v2[j]); } }
  if (h3) { u16x8 r = src[lane + 192];
#pragma unroll
    for (int j = 0; j < 8; j++) { v3[j] = h2f(r[j]); mx = fmaxf(mx, v3[j]); } }
  for (int off = 1; off < 64; off <<= 1) mx = fmaxf(mx, __shfl_xor(mx, off, 64));
  float s = 0.f;
  if (h0) {
#pragma unroll
    for (int j = 0; j < 8; j++) { v0[j] = __expf(v0[j] - mx); s += v0[j]; } }
  if (h1) {
#pragma unroll
    for (int j = 0; j < 8; j++) { v1[j] = __expf(v1[j] - mx); s += v1[j]; } }
  if (h2) {
#pragma unroll
    for (int j = 0; j < 8; j++) { v2[j] = __expf(v2[j] - mx); s += v2[j]; } }
  if (h3) {
#pragma unroll
    for (int j = 0; j < 8; j++) { v3[j] = __expf(v3[j] - mx); s += v3[j]; } }
  for (int off = 1; off < 64; off <<= 1) s += __shfl_xor(s, off, 64);
  float inv = 1.f / s;
  u16x8* dst = (u16x8*)(pb + rb);
  if (h0) { u16x8 o;
#pragma unroll
    for (int j = 0; j < 8; j++) o[j] = f2h(v0[j] * inv);
    dst[lane] = o; }
  if (h1) { u16x8 o;
#pragma unroll
    for (int j = 0; j < 8; j++) o[j] = f2h(v1[j] * inv);
    dst[lane + 64] = o; }
  if (h2) { u16x8 o;
#pragma unroll
    for (int j = 0; j < 8; j++) o[j] = f2h(v2[j] * inv);
    dst[lane + 128] = o; }
  if (h3) { u16x8 o;
#pragma unroll
    for (int j = 0; j < 8; j++) o[j] = f2h(v3[j] * inv);
    dst[lane + 192] = o; }
}

// ---- kernel 5: O = P Vt — 512 blocks, z-conjugate balance, f32 bounce epilogue ----
__global__ __launch_bounds__(256) void pv_gemm(const unsigned short* __restrict__ pb,
                                               const unsigned short* __restrict__ vtp,
                                               float* __restrict__ outp) {
  __shared__ unsigned short lds[2][16384];
  int bx = blockIdx.x;
  int n0 = blockIdx.y * 128;
  int bz = blockIdx.z;
  int qt = (bz & 2) ? (15 - bx) : bx;
  int b = bz;
  int tid = threadIdx.x, lane = tid & 63, w = tid >> 6;
  int wr = w >> 1, wc = w & 1, l15 = lane & 15, l4 = lane >> 4;
  const unsigned short* gB = vtp + (size_t)b * 1024 * 2048 + (size_t)n0 * 2048;
  int Wspan = (qt + 1) << 7;
  const unsigned short* gA = pb + (size_t)b * P_ELEMS + (size_t)16384 * (qt * (qt + 1) / 2);
  float* O = outp + ((size_t)b * 2048 + qt * 128) * 1024;
  f32x4 acc[4][4] = {};
  gemm_core(gA, gB, Wspan, 2048, &lds[0][0], &lds[1][0], 2 * (qt + 1),
            w, lane, wr, wc, l15, l4, acc);
  float* Tf = (float*)&lds[0][0];            // 128x128 f32, float4-chunk swizzle
#pragma unroll
  for (int m = 0; m < 4; m++)
#pragma unroll
    for (int n = 0; n < 4; n++) {
      int cl = wc * 64 + n * 16 + l15;
#pragma unroll
      for (int r = 0; r < 4; r++) {
        int rl = wr * 64 + m * 16 + l4 * 4 + r;
        int cc = cl >> 2;
        int sw = (((cc ^ (rl & 7)) << 2) | (cl & 3));
        Tf[rl * 128 + sw] = acc[m][n][r];
      }
    }
  __syncthreads();
#pragma unroll
  for (int i = 0; i < 16; i++) {
    int idx = i * 256 + tid;
    int row = idx >> 5, ch = idx & 31;
    float4 val = *(const float4*)&Tf[row * 128 + ((ch ^ (row & 7)) << 2)];
    *(float4*)&O[(size_t)row * 1024 + n0 + ch * 4] = val;
  }
}

extern "C" void kernel_launch(void* const* d_in, const int* in_sizes, int n_in,
                              void* d_out, int out_size, void* d_ws, size_t ws_size,
                              hipStream_t stream) {
  const float* x  = (const float*)d_in[0];
  const float* Wq = (const float*)d_in[1];
  const float* bq = (const float*)d_in[2];
  const float* Wk = (const float*)d_in[3];
  const float* bk = (const float*)d_in[4];
  const float* Wv = (const float*)d_in[5];
  const float* bv = (const float*)d_in[6];
  float* out = (float*)d_out;

  unsigned short* ws  = (unsigned short*)d_ws;
  unsigned short* wt  = ws;                          // 3,145,728 ushorts
  unsigned short* Qp  = ws + 3145728;                // 8,388,608
  unsigned short* Kp  = ws + 11534336;               // 8,388,608
  unsigned short* vtp = ws + 19922944;               // 8,388,608 (V^T [b][d][s])
  unsigned short* sc  = ws + 28311552;               // 4*P_ELEMS f16 scores
  unsigned short* pb  = ws + 37224448;               // 4*P_ELEMS f16 P
  unsigned short* xb  = (unsigned short*)d_out;      // x f16 scratch (overwritten by pv)

  cvt_fused<<<7168, 256, 0, stream>>>(x, Wq, Wk, Wv, xb, wt);
  qkv_gemm<<<dim3(64, 16), 256, 0, stream>>>(xb, wt, bq, bk, Qp, Kp);
  scores_v<<<992, 256, 0, stream>>>(Qp, Kp, xb, wt, bv, sc, vtp);
  softmax_row<<<2048, 256, 0, stream>>>(sc, pb);
  pv_gemm<<<dim3(16, 8, 4), 256, 0, stream>>>(pb, vtp, out);
}

// Round 18
// 148.102 us; speedup vs baseline: 1.0284x; 1.0284x over previous
//
#include <hip/hip_runtime.h>
#include <hip/hip_bf16.h>
#include <cstdint>

#define D_MODEL 1024
#define SEQ     2048
#define SCALE   0.125f
#define P_ELEMS 2228224   // per-batch packed triangular elems: 16384*136

typedef __attribute__((ext_vector_type(8))) _Float16 f16x8;
typedef __attribute__((ext_vector_type(8))) unsigned short u16x8;
typedef __attribute__((ext_vector_type(4))) float f32x4;

__device__ __forceinline__ unsigned short f2h(float f) {
  _Float16 h = (_Float16)f;
  return __builtin_bit_cast(unsigned short, h);
}
__device__ __forceinline__ float h2f(unsigned short u) {
  return (float)__builtin_bit_cast(_Float16, u);
}

__device__ __forceinline__ void gll16(const void* g, void* lds_p) {
  __builtin_amdgcn_global_load_lds(
      (const __attribute__((address_space(1))) unsigned int*)(uintptr_t)g,
      (__attribute__((address_space(3))) unsigned int*)(unsigned int)(uintptr_t)lds_p,
      16, 0, 0);
}

#define WAITV8 asm volatile("s_waitcnt vmcnt(8)" ::: "memory")
#define WAITV0 asm volatile("s_waitcnt vmcnt(0)" ::: "memory")
#define WAITL8 asm volatile("s_waitcnt lgkmcnt(8)" ::: "memory")
#define WAITL0 asm volatile("s_waitcnt lgkmcnt(0)" ::: "memory")
#define SCHEDB __builtin_amdgcn_sched_barrier(0)
#define BAR    __builtin_amdgcn_s_barrier()
#define PRIO1  __builtin_amdgcn_s_setprio(1)
#define PRIO0  __builtin_amdgcn_s_setprio(0)
#define MFMA16(a, b, c) __builtin_amdgcn_mfma_f32_16x16x32_f16(a, b, c, 0, 0, 0)

// ============ 128-tile pipeline (4 waves), 16x16x32 core (r14-verified) ============
__device__ __forceinline__ void stage_tile(const unsigned short* gA, const unsigned short* gB,
                                           size_t sA, size_t sB,
                                           int k0, unsigned short* buf, int w, int lane) {
  int rl = lane >> 3;
  int sg = ((lane & 7) ^ rl) << 3;
#pragma unroll
  for (int j = 0; j < 4; j++) {
    int c = w * 4 + j;
    int row = c * 8 + rl;
    gll16(gA + (size_t)row * sA + k0 + sg, buf + c * 512);
    gll16(gB + (size_t)row * sB + k0 + sg, buf + 8192 + c * 512);
  }
}

__device__ __forceinline__ void gemm_core(const unsigned short* gA, const unsigned short* gB,
                                          size_t sA, size_t sB,
                                          unsigned short* lds0, unsigned short* lds1, int nt,
                                          int w, int lane, int wr, int wc, int l15, int l4,
                                          f32x4 acc[4][4]) {
  stage_tile(gA, gB, sA, sB, 0, lds0, w, lane);
  stage_tile(gA, gB, sA, sB, 64, lds1, w, lane);
  WAITV8; SCHEDB; BAR;
  for (int t = 0; t < nt; t++) {
    const unsigned short* buf = (t & 1) ? lds1 : lds0;
    const unsigned short* bA = buf;
    const unsigned short* bB = buf + 8192;
    f16x8 a0[4], b0[4], a1[4], b1[4];
#pragma unroll
    for (int m = 0; m < 4; m++) {
      int row = wr * 64 + m * 16 + l15, rs = row & 7;
      a0[m] = *(const f16x8*)(bA + row * 64 + ((l4 ^ rs) << 3));
    }
#pragma unroll
    for (int n = 0; n < 4; n++) {
      int row = wc * 64 + n * 16 + l15, rs = row & 7;
      b0[n] = *(const f16x8*)(bB + row * 64 + ((l4 ^ rs) << 3));
    }
#pragma unroll
    for (int m = 0; m < 4; m++) {
      int row = wr * 64 + m * 16 + l15, rs = row & 7;
      a1[m] = *(const f16x8*)(bA + row * 64 + (((4 + l4) ^ rs) << 3));
    }
#pragma unroll
    for (int n = 0; n < 4; n++) {
      int row = wc * 64 + n * 16 + l15, rs = row & 7;
      b1[n] = *(const f16x8*)(bB + row * 64 + (((4 + l4) ^ rs) << 3));
    }
    WAITL8; SCHEDB;
    PRIO1;
#pragma unroll
    for (int m = 0; m < 4; m++)
#pragma unroll
      for (int n = 0; n < 4; n++)
        acc[m][n] = MFMA16(a0[m], b0[n], acc[m][n]);
    PRIO0;
    WAITL0; SCHEDB; BAR;
    if (t + 2 < nt) stage_tile(gA, gB, sA, sB, (t + 2) * 64,
                               (unsigned short*)buf, w, lane);
    PRIO1;
#pragma unroll
    for (int m = 0; m < 4; m++)
#pragma unroll
      for (int n = 0; n < 4; n++)
        acc[m][n] = MFMA16(a1[m], b1[n], acc[m][n]);
    PRIO0;
    if (t + 2 < nt) { WAITV8; } else { WAITV0; }
    SCHEDB; BAR;
  }
}

// ---- kernel 1: fused converts ----
__global__ __launch_bounds__(256) void cvt_fused(const float* __restrict__ x,
                                                 const float* __restrict__ W0,
                                                 const float* __restrict__ W1,
                                                 const float* __restrict__ W2,
                                                 unsigned short* __restrict__ xb,
                                                 unsigned short* __restrict__ wt) {
  __shared__ float t[32][33];
  int bid = blockIdx.x;
  int tid = threadIdx.x;
  if (bid < 4096) {
    int i = bid * 256 + tid;
    const float4* p = (const float4*)x + (size_t)i * 2;
    float4 a = p[0], b = p[1];
    u16x8 r;
    r[0] = f2h(a.x); r[1] = f2h(a.y); r[2] = f2h(a.z); r[3] = f2h(a.w);
    r[4] = f2h(b.x); r[5] = f2h(b.y); r[6] = f2h(b.z); r[7] = f2h(b.w);
    *((u16x8*)xb + i) = r;
  } else {
    int id = bid - 4096;
    int z = id >> 10, rem = id & 1023;
    int bx = rem & 31, by = rem >> 5;
    const float* W = (z == 0) ? W0 : (z == 1 ? W1 : W2);
    unsigned short* o = wt + (size_t)z * 1048576;
    int c0 = bx * 32, r0 = by * 32;
    int tx = tid & 31, ty = tid >> 5;
    for (int i = 0; i < 4; i++)
      t[ty + 8 * i][tx] = W[(size_t)(r0 + ty + 8 * i) * 1024 + c0 + tx];
    __syncthreads();
    for (int i = 0; i < 4; i++)
      o[(size_t)(c0 + ty + 8 * i) * 1024 + r0 + tx] = f2h(t[tx][ty + 8 * i]);
  }
}

// ---- kernel 2: QK GEMM only (1024 blocks = 2 exact rounds); LDS-bounce epilogue ----
__global__ __launch_bounds__(256) void qkv_gemm(const unsigned short* __restrict__ xb,
                                                const unsigned short* __restrict__ wt,
                                                const float* __restrict__ b0,
                                                const float* __restrict__ b1,
                                                unsigned short* __restrict__ Qp,
                                                unsigned short* __restrict__ Kp) {
  __shared__ unsigned short lds[2][16384];
  int m0 = blockIdx.x * 128;
  int n0 = blockIdx.y * 128;
  int z = n0 >> 10, nz = n0 & 1023;
  const unsigned short* gA = xb + (size_t)m0 * 1024;
  const unsigned short* gB = wt + (size_t)z * 1048576 + (size_t)nz * 1024;
  const float* bias = z ? b1 : b0;
  unsigned short* O = z ? Kp : Qp;
  int tid = threadIdx.x, lane = tid & 63, w = tid >> 6;
  int wr = w >> 1, wc = w & 1, l15 = lane & 15, l4 = lane >> 4;
  f32x4 acc[4][4] = {};
  gemm_core(gA, gB, 1024, 1024, &lds[0][0], &lds[1][0], 16, w, lane, wr, wc, l15, l4, acc);

  unsigned short* T = &lds[0][0];            // 128 x 136 f16 bounce
#pragma unroll
  for (int m = 0; m < 4; m++)
#pragma unroll
    for (int n = 0; n < 4; n++) {
      int cl = wc * 64 + n * 16 + l15;
      float bv = bias[nz + cl];
#pragma unroll
      for (int r = 0; r < 4; r++) {
        int rl = wr * 64 + m * 16 + l4 * 4 + r;
        T[rl * 136 + cl] = f2h(acc[m][n][r] + bv);
      }
    }
  __syncthreads();
#pragma unroll
  for (int i = 0; i < 8; i++) {
    int idx = i * 256 + tid;
    int row = idx >> 4, ch = idx & 15;
    u16x8 v = *(const u16x8*)(T + row * 136 + ch * 8);
    *(u16x8*)(O + (size_t)(m0 + row) * 1024 + nz + ch * 8) = v;
  }
}

// ---- kernel 3: fused scores (blk<512, doubles first) + V projection (blk>=512) ----
__global__ __launch_bounds__(256) void scores_v(const unsigned short* __restrict__ Q,
                                                const unsigned short* __restrict__ Kb,
                                                const unsigned short* __restrict__ xb,
                                                const unsigned short* __restrict__ wt,
                                                const float* __restrict__ bvf,
                                                unsigned short* __restrict__ sc,
                                                unsigned short* __restrict__ vtp) {
  __shared__ unsigned short lds[2][16384];
  int blk = blockIdx.x;
  int tid = threadIdx.x, lane = tid & 63, w = tid >> 6;
  int wr = w >> 1, wc = w & 1, l15 = lane & 15, l4 = lane >> 4;
  if (blk < 512) {
    int t0, ntile;
    if (blk < 32) { t0 = 480 + blk; ntile = 2; }
    else          { t0 = blk - 32;  ntile = 1; }
    for (int u = 0; u < ntile; u++) {
      int ti = t0 + u * 32;
      int b = ti / 136, i = ti % 136;
      int qt = (int)((sqrtf(8.f * i + 1.f) - 1.f) * 0.5f);
      while ((qt + 1) * (qt + 2) / 2 <= i) qt++;
      while (qt * (qt + 1) / 2 > i) qt--;
      int kt = i - qt * (qt + 1) / 2;
      int Wspan = (qt + 1) << 7;
      const unsigned short* gA = Q  + ((size_t)b * 2048 + qt * 128) * 1024;
      const unsigned short* gB = Kb + ((size_t)b * 2048 + kt * 128) * 1024;
      unsigned short* outp = sc + (size_t)b * P_ELEMS + (size_t)16384 * (qt * (qt + 1) / 2);
      f32x4 acc[4][4] = {};
      gemm_core(gA, gB, 1024, 1024, &lds[0][0], &lds[1][0], 16, w, lane, wr, wc, l15, l4, acc);
      unsigned short* T = &lds[0][0];
#pragma unroll
      for (int m = 0; m < 4; m++)
#pragma unroll
        for (int n = 0; n < 4; n++) {
          int cl = wc * 64 + n * 16 + l15;
          int kv = kt * 128 + cl;
#pragma unroll
          for (int r = 0; r < 4; r++) {
            int rl = wr * 64 + m * 16 + l4 * 4 + r;
            int srow = qt * 128 + rl;
            float v = acc[m][n][r] * SCALE;
            if (kv > srow) v = -30000.f;
            T[rl * 136 + cl] = f2h(v);
          }
        }
      __syncthreads();
#pragma unroll
      for (int i2 = 0; i2 < 8; i2++) {
        int idx = i2 * 256 + tid;
        int row = idx >> 4, ch = idx & 15;
        u16x8 v = *(const u16x8*)(T + row * 136 + ch * 8);
        *(u16x8*)(outp + (size_t)row * Wspan + kt * 128 + ch * 8) = v;
      }
      __syncthreads();
    }
  } else {
    int id = blk - 512;                       // 0..511
    int m0 = (id & 63) * 128;
    int n0v = (id >> 6) * 128;                // 0..896
    const unsigned short* gA = xb + (size_t)m0 * 1024;
    const unsigned short* gB = wt + (size_t)2 * 1048576 + (size_t)n0v * 1024;
    f32x4 acc[4][4] = {};
    gemm_core(gA, gB, 1024, 1024, &lds[0][0], &lds[1][0], 16, w, lane, wr, wc, l15, l4, acc);
    unsigned short* T = &lds[0][0];           // transposed bounce: T[d][s]
#pragma unroll
    for (int m = 0; m < 4; m++)
#pragma unroll
      for (int n = 0; n < 4; n++) {
        int cl = wc * 64 + n * 16 + l15;      // d-local
        float bvv = bvf[n0v + cl];
#pragma unroll
        for (int r = 0; r < 4; r++) {
          int rl = wr * 64 + m * 16 + l4 * 4 + r;    // s-local
          T[cl * 136 + rl] = f2h(acc[m][n][r] + bvv);
        }
      }
    __syncthreads();
    int bidx = m0 >> 11, s0 = m0 & 2047;
#pragma unroll
    for (int i = 0; i < 8; i++) {
      int d = w * 32 + i * 4 + (lane >> 4);
      int ch = lane & 15;
      u16x8 v = *(const u16x8*)(T + d * 136 + ch * 8);
      *(u16x8*)(vtp + ((size_t)bidx * 1024 + n0v + d) * 2048 + s0 + ch * 8) = v;
    }
  }
}

// ---- kernel 4: per-wave row softmax (4 same-width rows per block) ----
__global__ __launch_bounds__(256) void softmax_row(const unsigned short* __restrict__ sc,
                                                   unsigned short* __restrict__ pb) {
  int base = blockIdx.x * 4;
  int b = base >> 11, sl0 = base & 2047;
  int w = threadIdx.x >> 6, lane = threadIdx.x & 63;
  int sl = sl0 + w;
  int qt = sl >> 7;
  int Wspan = (qt + 1) << 7;
  size_t rb = (size_t)b * P_ELEMS + (size_t)16384 * (qt * (qt + 1) / 2) + (size_t)(sl & 127) * Wspan;
  const u16x8* src = (const u16x8*)(sc + rb);
  int nc = Wspan >> 3;
  bool h0 = lane < nc, h1 = lane + 64 < nc, h2 = lane + 128 < nc, h3 = lane + 192 < nc;
  float v0[8], v1[8], v2[8], v3[8];
  float mx = -1e30f;
  if (h0) { u16x8 r = src[lane];
#pragma unroll
    for (int j = 0; j < 8; j++) { v0[j] = h2f(r[j]); mx = fmaxf(mx, v0[j]); } }
  if (h1) { u16x8 r = src[lane + 64];
#pragma unroll
    for (int j = 0; j < 8; j++) { v1[j] = h2f(r[j]); mx = fmaxf(mx, v1[j]); } }
  if (h2) { u16x8 r = src[lane + 128];
#pragma unroll
    for (int j = 0; j < 8; j++) { v2[j] = h2f(r[j]); mx = fmaxf(mx, v2[j]); } }
  if (h3) { u16x8 r = src[lane + 192];
#pragma unroll
    for (int j = 0; j < 8; j++) { v3[j] = h2f(r[j]); mx = fmaxf(mx, v3[j]); } }
  for (int off = 1; off < 64; off <<= 1) mx = fmaxf(mx, __shfl_xor(mx, off, 64));
  float s = 0.f;
  if (h0) {
#pragma unroll
    for (int j = 0; j < 8; j++) { v0[j] = __expf(v0[j] - mx); s += v0[j]; } }
  if (h1) {
#pragma unroll
    for (int j = 0; j < 8; j++) { v1[j] = __expf(v1[j] - mx); s += v1[j]; } }
  if (h2) {
#pragma unroll
    for (int j = 0; j < 8; j++) { v2[j] = __expf(v2[j] - mx); s += v2[j]; } }
  if (h3) {
#pragma unroll
    for (int j = 0; j < 8; j++) { v3[j] = __expf(v3[j] - mx); s += v3[j]; } }
  for (int off = 1; off < 64; off <<= 1) s += __shfl_xor(s, off, 64);
  float inv = 1.f / s;
  u16x8* dst = (u16x8*)(pb + rb);
  if (h0) { u16x8 o;
#pragma unroll
    for (int j = 0; j < 8; j++) o[j] = f2h(v0[j] * inv);
    dst[lane] = o; }
  if (h1) { u16x8 o;
#pragma unroll
    for (int j = 0; j < 8; j++) o[j] = f2h(v1[j] * inv);
    dst[lane + 64] = o; }
  if (h2) { u16x8 o;
#pragma unroll
    for (int j = 0; j < 8; j++) o[j] = f2h(v2[j] * inv);
    dst[lane + 128] = o; }
  if (h3) { u16x8 o;
#pragma unroll
    for (int j = 0; j < 8; j++) o[j] = f2h(v3[j] * inv);
    dst[lane + 192] = o; }
}

// ---- kernel 5: O = P Vt — 512 blocks, z-conjugate balance, f32 bounce epilogue ----
__global__ __launch_bounds__(256) void pv_gemm(const unsigned short* __restrict__ pb,
                                               const unsigned short* __restrict__ vtp,
                                               float* __restrict__ outp) {
  __shared__ unsigned short lds[2][16384];
  int bx = blockIdx.x;
  int n0 = blockIdx.y * 128;
  int bz = blockIdx.z;
  int qt = (bz & 2) ? (15 - bx) : bx;
  int b = bz;
  int tid = threadIdx.x, lane = tid & 63, w = tid >> 6;
  int wr = w >> 1, wc = w & 1, l15 = lane & 15, l4 = lane >> 4;
  const unsigned short* gB = vtp + (size_t)b * 1024 * 2048 + (size_t)n0 * 2048;
  int Wspan = (qt + 1) << 7;
  const unsigned short* gA = pb + (size_t)b * P_ELEMS + (size_t)16384 * (qt * (qt + 1) / 2);
  float* O = outp + ((size_t)b * 2048 + qt * 128) * 1024;
  f32x4 acc[4][4] = {};
  gemm_core(gA, gB, Wspan, 2048, &lds[0][0], &lds[1][0], 2 * (qt + 1),
            w, lane, wr, wc, l15, l4, acc);
  float* Tf = (float*)&lds[0][0];            // 128x128 f32, float4-chunk swizzle
#pragma unroll
  for (int m = 0; m < 4; m++)
#pragma unroll
    for (int n = 0; n < 4; n++) {
      int cl = wc * 64 + n * 16 + l15;
#pragma unroll
      for (int r = 0; r < 4; r++) {
        int rl = wr * 64 + m * 16 + l4 * 4 + r;
        int cc = cl >> 2;
        int sw = (((cc ^ (rl & 7)) << 2) | (cl & 3));
        Tf[rl * 128 + sw] = acc[m][n][r];
      }
    }
  __syncthreads();
#pragma unroll
  for (int i = 0; i < 16; i++) {
    int idx = i * 256 + tid;
    int row = idx >> 5, ch = idx & 31;
    float4 val = *(const float4*)&Tf[row * 128 + ((ch ^ (row & 7)) << 2)];
    *(float4*)&O[(size_t)row * 1024 + n0 + ch * 4] = val;
  }
}

extern "C" void kernel_launch(void* const* d_in, const int* in_sizes, int n_in,
                              void* d_out, int out_size, void* d_ws, size_t ws_size,
                              hipStream_t stream) {
  const float* x  = (const float*)d_in[0];
  const float* Wq = (const float*)d_in[1];
  const float* bq = (const float*)d_in[2];
  const float* Wk = (const float*)d_in[3];
  const float* bk = (const float*)d_in[4];
  const float* Wv = (const float*)d_in[5];
  const float* bv = (const float*)d_in[6];
  float* out = (float*)d_out;

  unsigned short* ws  = (unsigned short*)d_ws;
  unsigned short* wt  = ws;                          // 3,145,728 ushorts
  unsigned short* Qp  = ws + 3145728;                // 8,388,608
  unsigned short* Kp  = ws + 11534336;               // 8,388,608
  unsigned short* vtp = ws + 19922944;               // 8,388,608 (V^T [b][d][s])
  unsigned short* sc  = ws + 28311552;               // 4*P_ELEMS f16 scores
  unsigned short* pb  = ws + 37224448;               // 4*P_ELEMS f16 P
  unsigned short* xb  = (unsigned short*)d_out;      // x f16 scratch (overwritten by pv)

  cvt_fused<<<7168, 256, 0, stream>>>(x, Wq, Wk, Wv, xb, wt);
  qkv_gemm<<<dim3(64, 16), 256, 0, stream>>>(xb, wt, bq, bk, Qp, Kp);
  scores_v<<<1024, 256, 0, stream>>>(Qp, Kp, xb, wt, bv, sc, vtp);
  softmax_row<<<2048, 256, 0, stream>>>(sc, pb);
  pv_gemm<<<dim3(16, 8, 4), 256, 0, stream>>>(pb, vtp, out);
}

// Round 19
// 142.498 us; speedup vs baseline: 1.0689x; 1.0393x over previous
//
#include <hip/hip_runtime.h>
#include <hip/hip_bf16.h>
#include <cstdint>

#define D_MODEL 1024
#define SEQ     2048
#define SCALE   0.125f
#define P_ELEMS 2228224   // per-batch packed triangular elems: 16384*136

typedef __attribute__((ext_vector_type(8))) _Float16 f16x8;
typedef __attribute__((ext_vector_type(8))) unsigned short u16x8;
typedef __attribute__((ext_vector_type(4))) float f32x4;

__device__ __forceinline__ unsigned short f2h(float f) {
  _Float16 h = (_Float16)f;
  return __builtin_bit_cast(unsigned short, h);
}
__device__ __forceinline__ float h2f(unsigned short u) {
  return (float)__builtin_bit_cast(_Float16, u);
}

__device__ __forceinline__ void gll16(const void* g, void* lds_p) {
  __builtin_amdgcn_global_load_lds(
      (const __attribute__((address_space(1))) unsigned int*)(uintptr_t)g,
      (__attribute__((address_space(3))) unsigned int*)(unsigned int)(uintptr_t)lds_p,
      16, 0, 0);
}

#define WAITV8 asm volatile("s_waitcnt vmcnt(8)" ::: "memory")
#define WAITV0 asm volatile("s_waitcnt vmcnt(0)" ::: "memory")
#define WAITL8 asm volatile("s_waitcnt lgkmcnt(8)" ::: "memory")
#define WAITL0 asm volatile("s_waitcnt lgkmcnt(0)" ::: "memory")
#define SCHEDB __builtin_amdgcn_sched_barrier(0)
#define BAR    __builtin_amdgcn_s_barrier()
#define PRIO1  __builtin_amdgcn_s_setprio(1)
#define PRIO0  __builtin_amdgcn_s_setprio(0)
#define MFMA16(a, b, c) __builtin_amdgcn_mfma_f32_16x16x32_f16(a, b, c, 0, 0, 0)

// ============ 128-tile pipeline (4 waves), 16x16x32 core (r14-verified) ============
__device__ __forceinline__ void stage_tile(const unsigned short* gA, const unsigned short* gB,
                                           size_t sA, size_t sB,
                                           int k0, unsigned short* buf, int w, int lane) {
  int rl = lane >> 3;
  int sg = ((lane & 7) ^ rl) << 3;
#pragma unroll
  for (int j = 0; j < 4; j++) {
    int c = w * 4 + j;
    int row = c * 8 + rl;
    gll16(gA + (size_t)row * sA + k0 + sg, buf + c * 512);
    gll16(gB + (size_t)row * sB + k0 + sg, buf + 8192 + c * 512);
  }
}

__device__ __forceinline__ void gemm_core(const unsigned short* gA, const unsigned short* gB,
                                          size_t sA, size_t sB,
                                          unsigned short* lds0, unsigned short* lds1, int nt,
                                          int w, int lane, int wr, int wc, int l15, int l4,
                                          f32x4 acc[4][4]) {
  stage_tile(gA, gB, sA, sB, 0, lds0, w, lane);
  stage_tile(gA, gB, sA, sB, 64, lds1, w, lane);
  WAITV8; SCHEDB; BAR;
  for (int t = 0; t < nt; t++) {
    const unsigned short* buf = (t & 1) ? lds1 : lds0;
    const unsigned short* bA = buf;
    const unsigned short* bB = buf + 8192;
    f16x8 a0[4], b0[4], a1[4], b1[4];
#pragma unroll
    for (int m = 0; m < 4; m++) {
      int row = wr * 64 + m * 16 + l15, rs = row & 7;
      a0[m] = *(const f16x8*)(bA + row * 64 + ((l4 ^ rs) << 3));
    }
#pragma unroll
    for (int n = 0; n < 4; n++) {
      int row = wc * 64 + n * 16 + l15, rs = row & 7;
      b0[n] = *(const f16x8*)(bB + row * 64 + ((l4 ^ rs) << 3));
    }
#pragma unroll
    for (int m = 0; m < 4; m++) {
      int row = wr * 64 + m * 16 + l15, rs = row & 7;
      a1[m] = *(const f16x8*)(bA + row * 64 + (((4 + l4) ^ rs) << 3));
    }
#pragma unroll
    for (int n = 0; n < 4; n++) {
      int row = wc * 64 + n * 16 + l15, rs = row & 7;
      b1[n] = *(const f16x8*)(bB + row * 64 + (((4 + l4) ^ rs) << 3));
    }
    WAITL8; SCHEDB;
    PRIO1;
#pragma unroll
    for (int m = 0; m < 4; m++)
#pragma unroll
      for (int n = 0; n < 4; n++)
        acc[m][n] = MFMA16(a0[m], b0[n], acc[m][n]);
    PRIO0;
    WAITL0; SCHEDB; BAR;
    if (t + 2 < nt) stage_tile(gA, gB, sA, sB, (t + 2) * 64,
                               (unsigned short*)buf, w, lane);
    PRIO1;
#pragma unroll
    for (int m = 0; m < 4; m++)
#pragma unroll
      for (int n = 0; n < 4; n++)
        acc[m][n] = MFMA16(a1[m], b1[n], acc[m][n]);
    PRIO0;
    if (t + 2 < nt) { WAITV8; } else { WAITV0; }
    SCHEDB; BAR;
  }
}

// ---- kernel 1: fused converts ----
__global__ __launch_bounds__(256) void cvt_fused(const float* __restrict__ x,
                                                 const float* __restrict__ W0,
                                                 const float* __restrict__ W1,
                                                 const float* __restrict__ W2,
                                                 unsigned short* __restrict__ xb,
                                                 unsigned short* __restrict__ wt) {
  __shared__ float t[32][33];
  int bid = blockIdx.x;
  int tid = threadIdx.x;
  if (bid < 4096) {
    int i = bid * 256 + tid;
    const float4* p = (const float4*)x + (size_t)i * 2;
    float4 a = p[0], b = p[1];
    u16x8 r;
    r[0] = f2h(a.x); r[1] = f2h(a.y); r[2] = f2h(a.z); r[3] = f2h(a.w);
    r[4] = f2h(b.x); r[5] = f2h(b.y); r[6] = f2h(b.z); r[7] = f2h(b.w);
    *((u16x8*)xb + i) = r;
  } else {
    int id = bid - 4096;
    int z = id >> 10, rem = id & 1023;
    int bx = rem & 31, by = rem >> 5;
    const float* W = (z == 0) ? W0 : (z == 1 ? W1 : W2);
    unsigned short* o = wt + (size_t)z * 1048576;
    int c0 = bx * 32, r0 = by * 32;
    int tx = tid & 31, ty = tid >> 5;
    for (int i = 0; i < 4; i++)
      t[ty + 8 * i][tx] = W[(size_t)(r0 + ty + 8 * i) * 1024 + c0 + tx];
    __syncthreads();
    for (int i = 0; i < 4; i++)
      o[(size_t)(c0 + ty + 8 * i) * 1024 + r0 + tx] = f2h(t[tx][ty + 8 * i]);
  }
}

// ---- kernel 2: QK GEMM only (1024 blocks = 2 exact rounds); LDS-bounce epilogue ----
__global__ __launch_bounds__(256) void qkv_gemm(const unsigned short* __restrict__ xb,
                                                const unsigned short* __restrict__ wt,
                                                const float* __restrict__ b0,
                                                const float* __restrict__ b1,
                                                unsigned short* __restrict__ Qp,
                                                unsigned short* __restrict__ Kp) {
  __shared__ unsigned short lds[2][16384];
  int m0 = blockIdx.x * 128;
  int n0 = blockIdx.y * 128;
  int z = n0 >> 10, nz = n0 & 1023;
  const unsigned short* gA = xb + (size_t)m0 * 1024;
  const unsigned short* gB = wt + (size_t)z * 1048576 + (size_t)nz * 1024;
  const float* bias = z ? b1 : b0;
  unsigned short* O = z ? Kp : Qp;
  int tid = threadIdx.x, lane = tid & 63, w = tid >> 6;
  int wr = w >> 1, wc = w & 1, l15 = lane & 15, l4 = lane >> 4;
  f32x4 acc[4][4] = {};
  gemm_core(gA, gB, 1024, 1024, &lds[0][0], &lds[1][0], 16, w, lane, wr, wc, l15, l4, acc);

  unsigned short* T = &lds[0][0];            // 128 x 136 f16 bounce
#pragma unroll
  for (int m = 0; m < 4; m++)
#pragma unroll
    for (int n = 0; n < 4; n++) {
      int cl = wc * 64 + n * 16 + l15;
      float bv = bias[nz + cl];
#pragma unroll
      for (int r = 0; r < 4; r++) {
        int rl = wr * 64 + m * 16 + l4 * 4 + r;
        T[rl * 136 + cl] = f2h(acc[m][n][r] + bv);
      }
    }
  __syncthreads();
#pragma unroll
  for (int i = 0; i < 8; i++) {
    int idx = i * 256 + tid;
    int row = idx >> 4, ch = idx & 15;
    u16x8 v = *(const u16x8*)(T + row * 136 + ch * 8);
    *(u16x8*)(O + (size_t)(m0 + row) * 1024 + nz + ch * 8) = v;
  }
}

// 4x4 super-block tile ordering for score tiles: 16 consecutive tiles touch
// 4 Q-panels + 4 K-panels (2 MB, L2-resident) instead of 1 Q + 16 K.
__device__ __constant__ int sq_base[10] = {0, 10, 26, 36, 52, 68, 78, 94, 110, 126};
__device__ __constant__ int sq_q[10]    = {0, 1, 1, 2, 2, 2, 3, 3, 3, 3};
__device__ __constant__ int sq_k[10]    = {0, 0, 1, 0, 1, 2, 0, 1, 2, 3};
__device__ __constant__ int sq_d[10]    = {1, 0, 1, 0, 0, 1, 0, 0, 0, 1};
__device__ __constant__ int dq_[10]     = {0, 1, 1, 2, 2, 2, 3, 3, 3, 3};
__device__ __constant__ int dk_[10]     = {0, 0, 1, 0, 1, 2, 0, 1, 2, 3};

__device__ __forceinline__ void map_tile(int u, int* qt_out, int* kt_out) {
  int s = 0;
#pragma unroll
  for (int j = 1; j < 10; j++) s += (u >= sq_base[j]);
  int loc = u - sq_base[s];
  int qt, kt;
  if (sq_d[s]) { qt = 4 * sq_q[s] + dq_[loc]; kt = 4 * sq_k[s] + dk_[loc]; }
  else         { qt = 4 * sq_q[s] + (loc >> 2); kt = 4 * sq_k[s] + (loc & 3); }
  *qt_out = qt; *kt_out = kt;
}

// ---- kernel 3: fused scores (blk<512, doubles first) + V projection (blk>=512) ----
__global__ __launch_bounds__(256) void scores_v(const unsigned short* __restrict__ Q,
                                                const unsigned short* __restrict__ Kb,
                                                const unsigned short* __restrict__ xb,
                                                const unsigned short* __restrict__ wt,
                                                const float* __restrict__ bvf,
                                                unsigned short* __restrict__ sc,
                                                unsigned short* __restrict__ vtp) {
  __shared__ unsigned short lds[2][16384];
  int blk = blockIdx.x;
  int tid = threadIdx.x, lane = tid & 63, w = tid >> 6;
  int wr = w >> 1, wc = w & 1, l15 = lane & 15, l4 = lane >> 4;
  if (blk < 512) {
    int t0, ntile;
    if (blk < 32) { t0 = 480 + blk; ntile = 2; }
    else          { t0 = blk - 32;  ntile = 1; }
    for (int u = 0; u < ntile; u++) {
      int ti = t0 + u * 32;
      int b = ti / 136, i = ti % 136;
      int qt, kt;
      map_tile(i, &qt, &kt);
      int Wspan = (qt + 1) << 7;
      const unsigned short* gA = Q  + ((size_t)b * 2048 + qt * 128) * 1024;
      const unsigned short* gB = Kb + ((size_t)b * 2048 + kt * 128) * 1024;
      unsigned short* outp = sc + (size_t)b * P_ELEMS + (size_t)16384 * (qt * (qt + 1) / 2);
      f32x4 acc[4][4] = {};
      gemm_core(gA, gB, 1024, 1024, &lds[0][0], &lds[1][0], 16, w, lane, wr, wc, l15, l4, acc);
      unsigned short* T = &lds[0][0];
#pragma unroll
      for (int m = 0; m < 4; m++)
#pragma unroll
        for (int n = 0; n < 4; n++) {
          int cl = wc * 64 + n * 16 + l15;
          int kv = kt * 128 + cl;
#pragma unroll
          for (int r = 0; r < 4; r++) {
            int rl = wr * 64 + m * 16 + l4 * 4 + r;
            int srow = qt * 128 + rl;
            float v = acc[m][n][r] * SCALE;
            if (kv > srow) v = -30000.f;
            T[rl * 136 + cl] = f2h(v);
          }
        }
      __syncthreads();
#pragma unroll
      for (int i2 = 0; i2 < 8; i2++) {
        int idx = i2 * 256 + tid;
        int row = idx >> 4, ch = idx & 15;
        u16x8 v = *(const u16x8*)(T + row * 136 + ch * 8);
        *(u16x8*)(outp + (size_t)row * Wspan + kt * 128 + ch * 8) = v;
      }
      __syncthreads();
    }
  } else {
    int id = blk - 512;                       // 0..511
    int m0 = (id & 63) * 128;
    int n0v = (id >> 6) * 128;                // 0..896
    const unsigned short* gA = xb + (size_t)m0 * 1024;
    const unsigned short* gB = wt + (size_t)2 * 1048576 + (size_t)n0v * 1024;
    f32x4 acc[4][4] = {};
    gemm_core(gA, gB, 1024, 1024, &lds[0][0], &lds[1][0], 16, w, lane, wr, wc, l15, l4, acc);
    unsigned short* T = &lds[0][0];           // transposed bounce: T[d][s]
#pragma unroll
    for (int m = 0; m < 4; m++)
#pragma unroll
      for (int n = 0; n < 4; n++) {
        int cl = wc * 64 + n * 16 + l15;      // d-local
        float bvv = bvf[n0v + cl];
#pragma unroll
        for (int r = 0; r < 4; r++) {
          int rl = wr * 64 + m * 16 + l4 * 4 + r;    // s-local
          T[cl * 136 + rl] = f2h(acc[m][n][r] + bvv);
        }
      }
    __syncthreads();
    int bidx = m0 >> 11, s0 = m0 & 2047;
#pragma unroll
    for (int i = 0; i < 8; i++) {
      int d = w * 32 + i * 4 + (lane >> 4);
      int ch = lane & 15;
      u16x8 v = *(const u16x8*)(T + d * 136 + ch * 8);
      *(u16x8*)(vtp + ((size_t)bidx * 1024 + n0v + d) * 2048 + s0 + ch * 8) = v;
    }
  }
}

// ---- kernel 4: per-wave row softmax (4 same-width rows per block) ----
__global__ __launch_bounds__(256) void softmax_row(const unsigned short* __restrict__ sc,
                                                   unsigned short* __restrict__ pb) {
  int base = blockIdx.x * 4;
  int b = base >> 11, sl0 = base & 2047;
  int w = threadIdx.x >> 6, lane = threadIdx.x & 63;
  int sl = sl0 + w;
  int qt = sl >> 7;
  int Wspan = (qt + 1) << 7;
  size_t rb = (size_t)b * P_ELEMS + (size_t)16384 * (qt * (qt + 1) / 2) + (size_t)(sl & 127) * Wspan;
  const u16x8* src = (const u16x8*)(sc + rb);
  int nc = Wspan >> 3;
  bool h0 = lane < nc, h1 = lane + 64 < nc, h2 = lane + 128 < nc, h3 = lane + 192 < nc;
  float v0[8], v1[8], v2[8], v3[8];
  float mx = -1e30f;
  if (h0) { u16x8 r = src[lane];
#pragma unroll
    for (int j = 0; j < 8; j++) { v0[j] = h2f(r[j]); mx = fmaxf(mx, v0[j]); } }
  if (h1) { u16x8 r = src[lane + 64];
#pragma unroll
    for (int j = 0; j < 8; j++) { v1[j] = h2f(r[j]); mx = fmaxf(mx, v1[j]); } }
  if (h2) { u16x8 r = src[lane + 128];
#pragma unroll
    for (int j = 0; j < 8; j++) { v2[j] = h2f(r[j]); mx = fmaxf(mx, v2[j]); } }
  if (h3) { u16x8 r = src[lane + 192];
#pragma unroll
    for (int j = 0; j < 8; j++) { v3[j] = h2f(r[j]); mx = fmaxf(mx, v3[j]); } }
  for (int off = 1; off < 64; off <<= 1) mx = fmaxf(mx, __shfl_xor(mx, off, 64));
  float s = 0.f;
  if (h0) {
#pragma unroll
    for (int j = 0; j < 8; j++) { v0[j] = __expf(v0[j] - mx); s += v0[j]; } }
  if (h1) {
#pragma unroll
    for (int j = 0; j < 8; j++) { v1[j] = __expf(v1[j] - mx); s += v1[j]; } }
  if (h2) {
#pragma unroll
    for (int j = 0; j < 8; j++) { v2[j] = __expf(v2[j] - mx); s += v2[j]; } }
  if (h3) {
#pragma unroll
    for (int j = 0; j < 8; j++) { v3[j] = __expf(v3[j] - mx); s += v3[j]; } }
  for (int off = 1; off < 64; off <<= 1) s += __shfl_xor(s, off, 64);
  float inv = 1.f / s;
  u16x8* dst = (u16x8*)(pb + rb);
  if (h0) { u16x8 o;
#pragma unroll
    for (int j = 0; j < 8; j++) o[j] = f2h(v0[j] * inv);
    dst[lane] = o; }
  if (h1) { u16x8 o;
#pragma unroll
    for (int j = 0; j < 8; j++) o[j] = f2h(v1[j] * inv);
    dst[lane + 64] = o; }
  if (h2) { u16x8 o;
#pragma unroll
    for (int j = 0; j < 8; j++) o[j] = f2h(v2[j] * inv);
    dst[lane + 128] = o; }
  if (h3) { u16x8 o;
#pragma unroll
    for (int j = 0; j < 8; j++) o[j] = f2h(v3[j] * inv);
    dst[lane + 192] = o; }
}

// ---- kernel 5: O = P Vt — 512 blocks, z-conjugate balance, f32 bounce epilogue ----
__global__ __launch_bounds__(256) void pv_gemm(const unsigned short* __restrict__ pb,
                                               const unsigned short* __restrict__ vtp,
                                               float* __restrict__ outp) {
  __shared__ unsigned short lds[2][16384];
  int bx = blockIdx.x;
  int n0 = blockIdx.y * 128;
  int bz = blockIdx.z;
  int qt = (bz & 2) ? (15 - bx) : bx;
  int b = bz;
  int tid = threadIdx.x, lane = tid & 63, w = tid >> 6;
  int wr = w >> 1, wc = w & 1, l15 = lane & 15, l4 = lane >> 4;
  const unsigned short* gB = vtp + (size_t)b * 1024 * 2048 + (size_t)n0 * 2048;
  int Wspan = (qt + 1) << 7;
  const unsigned short* gA = pb + (size_t)b * P_ELEMS + (size_t)16384 * (qt * (qt + 1) / 2);
  float* O = outp + ((size_t)b * 2048 + qt * 128) * 1024;
  f32x4 acc[4][4] = {};
  gemm_core(gA, gB, Wspan, 2048, &lds[0][0], &lds[1][0], 2 * (qt + 1),
            w, lane, wr, wc, l15, l4, acc);
  float* Tf = (float*)&lds[0][0];            // 128x128 f32, float4-chunk swizzle
#pragma unroll
  for (int m = 0; m < 4; m++)
#pragma unroll
    for (int n = 0; n < 4; n++) {
      int cl = wc * 64 + n * 16 + l15;
#pragma unroll
      for (int r = 0; r < 4; r++) {
        int rl = wr * 64 + m * 16 + l4 * 4 + r;
        int cc = cl >> 2;
        int sw = (((cc ^ (rl & 7)) << 2) | (cl & 3));
        Tf[rl * 128 + sw] = acc[m][n][r];
      }
    }
  __syncthreads();
#pragma unroll
  for (int i = 0; i < 16; i++) {
    int idx = i * 256 + tid;
    int row = idx >> 5, ch = idx & 31;
    float4 val = *(const float4*)&Tf[row * 128 + ((ch ^ (row & 7)) << 2)];
    *(float4*)&O[(size_t)row * 1024 + n0 + ch * 4] = val;
  }
}

extern "C" void kernel_launch(void* const* d_in, const int* in_sizes, int n_in,
                              void* d_out, int out_size, void* d_ws, size_t ws_size,
                              hipStream_t stream) {
  const float* x  = (const float*)d_in[0];
  const float* Wq = (const float*)d_in[1];
  const float* bq = (const float*)d_in[2];
  const float* Wk = (const float*)d_in[3];
  const float* bk = (const float*)d_in[4];
  const float* Wv = (const float*)d_in[5];
  const float* bv = (const float*)d_in[6];
  float* out = (float*)d_out;

  unsigned short* ws  = (unsigned short*)d_ws;
  unsigned short* wt  = ws;                          // 3,145,728 ushorts
  unsigned short* Qp  = ws + 3145728;                // 8,388,608
  unsigned short* Kp  = ws + 11534336;               // 8,388,608
  unsigned short* vtp = ws + 19922944;               // 8,388,608 (V^T [b][d][s])
  unsigned short* sc  = ws + 28311552;               // 4*P_ELEMS f16 scores
  unsigned short* pb  = ws + 37224448;               // 4*P_ELEMS f16 P
  unsigned short* xb  = (unsigned short*)d_out;      // x f16 scratch (overwritten by pv)

  cvt_fused<<<7168, 256, 0, stream>>>(x, Wq, Wk, Wv, xb, wt);
  qkv_gemm<<<dim3(64, 16), 256, 0, stream>>>(xb, wt, bq, bk, Qp, Kp);
  scores_v<<<1024, 256, 0, stream>>>(Qp, Kp, xb, wt, bv, sc, vtp);
  softmax_row<<<2048, 256, 0, stream>>>(sc, pb);
  pv_gemm<<<dim3(16, 8, 4), 256, 0, stream>>>(pb, vtp, out);
}

// Round 20
// 139.999 us; speedup vs baseline: 1.0880x; 1.0179x over previous
//
#include <hip/hip_runtime.h>
#include <hip/hip_bf16.h>
#include <cstdint>

#define D_MODEL 1024
#define SEQ     2048
#define SCALE   0.125f
#define P_ELEMS 2228224   // per-batch packed triangular elems: 16384*136

typedef __attribute__((ext_vector_type(8))) _Float16 f16x8;
typedef __attribute__((ext_vector_type(8))) unsigned short u16x8;
typedef __attribute__((ext_vector_type(4))) float f32x4;

__device__ __forceinline__ unsigned short f2h(float f) {
  _Float16 h = (_Float16)f;
  return __builtin_bit_cast(unsigned short, h);
}
__device__ __forceinline__ float h2f(unsigned short u) {
  return (float)__builtin_bit_cast(_Float16, u);
}

__device__ __forceinline__ void gll16(const void* g, void* lds_p) {
  __builtin_amdgcn_global_load_lds(
      (const __attribute__((address_space(1))) unsigned int*)(uintptr_t)g,
      (__attribute__((address_space(3))) unsigned int*)(unsigned int)(uintptr_t)lds_p,
      16, 0, 0);
}

#define WAITV8 asm volatile("s_waitcnt vmcnt(8)" ::: "memory")
#define WAITV0 asm volatile("s_waitcnt vmcnt(0)" ::: "memory")
#define WAITL8 asm volatile("s_waitcnt lgkmcnt(8)" ::: "memory")
#define WAITL0 asm volatile("s_waitcnt lgkmcnt(0)" ::: "memory")
#define SCHEDB __builtin_amdgcn_sched_barrier(0)
#define BAR    __builtin_amdgcn_s_barrier()
#define PRIO1  __builtin_amdgcn_s_setprio(1)
#define PRIO0  __builtin_amdgcn_s_setprio(0)
#define MFMA16(a, b, c) __builtin_amdgcn_mfma_f32_16x16x32_f16(a, b, c, 0, 0, 0)

// ============ 128-tile pipeline (4 waves), 16x16x32 core (r14-verified) ============
__device__ __forceinline__ void stage_tile(const unsigned short* gA, const unsigned short* gB,
                                           size_t sA, size_t sB,
                                           int k0, unsigned short* buf, int w, int lane) {
  int rl = lane >> 3;
  int sg = ((lane & 7) ^ rl) << 3;
#pragma unroll
  for (int j = 0; j < 4; j++) {
    int c = w * 4 + j;
    int row = c * 8 + rl;
    gll16(gA + (size_t)row * sA + k0 + sg, buf + c * 512);
    gll16(gB + (size_t)row * sB + k0 + sg, buf + 8192 + c * 512);
  }
}

__device__ __forceinline__ void gemm_core(const unsigned short* gA, const unsigned short* gB,
                                          size_t sA, size_t sB,
                                          unsigned short* lds0, unsigned short* lds1, int nt,
                                          int w, int lane, int wr, int wc, int l15, int l4,
                                          f32x4 acc[4][4]) {
  stage_tile(gA, gB, sA, sB, 0, lds0, w, lane);
  stage_tile(gA, gB, sA, sB, 64, lds1, w, lane);
  WAITV8; SCHEDB; BAR;
  for (int t = 0; t < nt; t++) {
    const unsigned short* buf = (t & 1) ? lds1 : lds0;
    const unsigned short* bA = buf;
    const unsigned short* bB = buf + 8192;
    f16x8 a0[4], b0[4], a1[4], b1[4];
#pragma unroll
    for (int m = 0; m < 4; m++) {
      int row = wr * 64 + m * 16 + l15, rs = row & 7;
      a0[m] = *(const f16x8*)(bA + row * 64 + ((l4 ^ rs) << 3));
    }
#pragma unroll
    for (int n = 0; n < 4; n++) {
      int row = wc * 64 + n * 16 + l15, rs = row & 7;
      b0[n] = *(const f16x8*)(bB + row * 64 + ((l4 ^ rs) << 3));
    }
#pragma unroll
    for (int m = 0; m < 4; m++) {
      int row = wr * 64 + m * 16 + l15, rs = row & 7;
      a1[m] = *(const f16x8*)(bA + row * 64 + (((4 + l4) ^ rs) << 3));
    }
#pragma unroll
    for (int n = 0; n < 4; n++) {
      int row = wc * 64 + n * 16 + l15, rs = row & 7;
      b1[n] = *(const f16x8*)(bB + row * 64 + (((4 + l4) ^ rs) << 3));
    }
    WAITL8; SCHEDB;
    PRIO1;
#pragma unroll
    for (int m = 0; m < 4; m++)
#pragma unroll
      for (int n = 0; n < 4; n++)
        acc[m][n] = MFMA16(a0[m], b0[n], acc[m][n]);
    PRIO0;
    WAITL0; SCHEDB; BAR;
    if (t + 2 < nt) stage_tile(gA, gB, sA, sB, (t + 2) * 64,
                               (unsigned short*)buf, w, lane);
    PRIO1;
#pragma unroll
    for (int m = 0; m < 4; m++)
#pragma unroll
      for (int n = 0; n < 4; n++)
        acc[m][n] = MFMA16(a1[m], b1[n], acc[m][n]);
    PRIO0;
    if (t + 2 < nt) { WAITV8; } else { WAITV0; }
    SCHEDB; BAR;
  }
}

// ---- kernel 1: fused converts ----
__global__ __launch_bounds__(256) void cvt_fused(const float* __restrict__ x,
                                                 const float* __restrict__ W0,
                                                 const float* __restrict__ W1,
                                                 const float* __restrict__ W2,
                                                 unsigned short* __restrict__ xb,
                                                 unsigned short* __restrict__ wt) {
  __shared__ float t[32][33];
  int bid = blockIdx.x;
  int tid = threadIdx.x;
  if (bid < 4096) {
    int i = bid * 256 + tid;
    const float4* p = (const float4*)x + (size_t)i * 2;
    float4 a = p[0], b = p[1];
    u16x8 r;
    r[0] = f2h(a.x); r[1] = f2h(a.y); r[2] = f2h(a.z); r[3] = f2h(a.w);
    r[4] = f2h(b.x); r[5] = f2h(b.y); r[6] = f2h(b.z); r[7] = f2h(b.w);
    *((u16x8*)xb + i) = r;
  } else {
    int id = bid - 4096;
    int z = id >> 10, rem = id & 1023;
    int bx = rem & 31, by = rem >> 5;
    const float* W = (z == 0) ? W0 : (z == 1 ? W1 : W2);
    unsigned short* o = wt + (size_t)z * 1048576;
    int c0 = bx * 32, r0 = by * 32;
    int tx = tid & 31, ty = tid >> 5;
    for (int i = 0; i < 4; i++)
      t[ty + 8 * i][tx] = W[(size_t)(r0 + ty + 8 * i) * 1024 + c0 + tx];
    __syncthreads();
    for (int i = 0; i < 4; i++)
      o[(size_t)(c0 + ty + 8 * i) * 1024 + r0 + tx] = f2h(t[tx][ty + 8 * i]);
  }
}

// ---- kernel 2: QK GEMM only (1024 blocks = 2 exact rounds); LDS-bounce epilogue ----
__global__ __launch_bounds__(256) void qkv_gemm(const unsigned short* __restrict__ xb,
                                                const unsigned short* __restrict__ wt,
                                                const float* __restrict__ b0,
                                                const float* __restrict__ b1,
                                                unsigned short* __restrict__ Qp,
                                                unsigned short* __restrict__ Kp) {
  __shared__ unsigned short lds[2][16384];
  int m0 = blockIdx.x * 128;
  int n0 = blockIdx.y * 128;
  int z = n0 >> 10, nz = n0 & 1023;
  const unsigned short* gA = xb + (size_t)m0 * 1024;
  const unsigned short* gB = wt + (size_t)z * 1048576 + (size_t)nz * 1024;
  const float* bias = z ? b1 : b0;
  unsigned short* O = z ? Kp : Qp;
  int tid = threadIdx.x, lane = tid & 63, w = tid >> 6;
  int wr = w >> 1, wc = w & 1, l15 = lane & 15, l4 = lane >> 4;
  f32x4 acc[4][4] = {};
  gemm_core(gA, gB, 1024, 1024, &lds[0][0], &lds[1][0], 16, w, lane, wr, wc, l15, l4, acc);

  unsigned short* T = &lds[0][0];            // 128 x 136 f16 bounce
#pragma unroll
  for (int m = 0; m < 4; m++)
#pragma unroll
    for (int n = 0; n < 4; n++) {
      int cl = wc * 64 + n * 16 + l15;
      float bv = bias[nz + cl];
#pragma unroll
      for (int r = 0; r < 4; r++) {
        int rl = wr * 64 + m * 16 + l4 * 4 + r;
        T[rl * 136 + cl] = f2h(acc[m][n][r] + bv);
      }
    }
  __syncthreads();
#pragma unroll
  for (int i = 0; i < 8; i++) {
    int idx = i * 256 + tid;
    int row = idx >> 4, ch = idx & 15;
    u16x8 v = *(const u16x8*)(T + row * 136 + ch * 8);
    *(u16x8*)(O + (size_t)(m0 + row) * 1024 + nz + ch * 8) = v;
  }
}

// 4x4 super-block tile ordering for score tiles (r19-verified).
__device__ __constant__ int sq_base[10] = {0, 10, 26, 36, 52, 68, 78, 94, 110, 126};
__device__ __constant__ int sq_q[10]    = {0, 1, 1, 2, 2, 2, 3, 3, 3, 3};
__device__ __constant__ int sq_k[10]    = {0, 0, 1, 0, 1, 2, 0, 1, 2, 3};
__device__ __constant__ int sq_d[10]    = {1, 0, 1, 0, 0, 1, 0, 0, 0, 1};
__device__ __constant__ int dq_[10]     = {0, 1, 1, 2, 2, 2, 3, 3, 3, 3};
__device__ __constant__ int dk_[10]     = {0, 0, 1, 0, 1, 2, 0, 1, 2, 3};

__device__ __forceinline__ void map_tile(int u, int* qt_out, int* kt_out) {
  int s = 0;
#pragma unroll
  for (int j = 1; j < 10; j++) s += (u >= sq_base[j]);
  int loc = u - sq_base[s];
  int qt, kt;
  if (sq_d[s]) { qt = 4 * sq_q[s] + dq_[loc]; kt = 4 * sq_k[s] + dk_[loc]; }
  else         { qt = 4 * sq_q[s] + (loc >> 2); kt = 4 * sq_k[s] + (loc & 3); }
  *qt_out = qt; *kt_out = kt;
}

// ---- kernel 3: fused scores + V; singles XCD-chunked (XCD c gets 60 consecutive units) ----
__global__ __launch_bounds__(256) void scores_v(const unsigned short* __restrict__ Q,
                                                const unsigned short* __restrict__ Kb,
                                                const unsigned short* __restrict__ xb,
                                                const unsigned short* __restrict__ wt,
                                                const float* __restrict__ bvf,
                                                unsigned short* __restrict__ sc,
                                                unsigned short* __restrict__ vtp) {
  __shared__ unsigned short lds[2][16384];
  int blk = blockIdx.x;
  int tid = threadIdx.x, lane = tid & 63, w = tid >> 6;
  int wr = w >> 1, wc = w & 1, l15 = lane & 15, l4 = lane >> 4;
  if (blk < 512) {
    int t0, ntile;
    if (blk < 32) { t0 = 480 + blk; ntile = 2; }   // doubles: units {480+blk, 512+blk}
    else {
      // XCD-coherent chunking of 480 single units: XCD c (= blk%8) walks
      // units [c*60, c*60+60) in super-block order -> ~2 MB live panel set per L2.
      int q = blk - 32;                            // 0..479; (q+32)%8 == q%8 == XCD
      t0 = (q % 8) * 60 + q / 8;                   // bijective (480 = 8*60)
      ntile = 1;
    }
    for (int u = 0; u < ntile; u++) {
      int ti = t0 + u * 32;
      int b = ti / 136, i = ti % 136;
      int qt, kt;
      map_tile(i, &qt, &kt);
      int Wspan = (qt + 1) << 7;
      const unsigned short* gA = Q  + ((size_t)b * 2048 + qt * 128) * 1024;
      const unsigned short* gB = Kb + ((size_t)b * 2048 + kt * 128) * 1024;
      unsigned short* outp = sc + (size_t)b * P_ELEMS + (size_t)16384 * (qt * (qt + 1) / 2);
      f32x4 acc[4][4] = {};
      gemm_core(gA, gB, 1024, 1024, &lds[0][0], &lds[1][0], 16, w, lane, wr, wc, l15, l4, acc);
      unsigned short* T = &lds[0][0];
#pragma unroll
      for (int m = 0; m < 4; m++)
#pragma unroll
        for (int n = 0; n < 4; n++) {
          int cl = wc * 64 + n * 16 + l15;
          int kv = kt * 128 + cl;
#pragma unroll
          for (int r = 0; r < 4; r++) {
            int rl = wr * 64 + m * 16 + l4 * 4 + r;
            int srow = qt * 128 + rl;
            float v = acc[m][n][r] * SCALE;
            if (kv > srow) v = -30000.f;
            T[rl * 136 + cl] = f2h(v);
          }
        }
      __syncthreads();
#pragma unroll
      for (int i2 = 0; i2 < 8; i2++) {
        int idx = i2 * 256 + tid;
        int row = idx >> 4, ch = idx & 15;
        u16x8 v = *(const u16x8*)(T + row * 136 + ch * 8);
        *(u16x8*)(outp + (size_t)row * Wspan + kt * 128 + ch * 8) = v;
      }
      __syncthreads();
    }
  } else {
    int id = blk - 512;                       // 0..511
    int m0 = (id & 63) * 128;
    int n0v = (id >> 6) * 128;                // 0..896
    const unsigned short* gA = xb + (size_t)m0 * 1024;
    const unsigned short* gB = wt + (size_t)2 * 1048576 + (size_t)n0v * 1024;
    f32x4 acc[4][4] = {};
    gemm_core(gA, gB, 1024, 1024, &lds[0][0], &lds[1][0], 16, w, lane, wr, wc, l15, l4, acc);
    unsigned short* T = &lds[0][0];           // transposed bounce: T[d][s]
#pragma unroll
    for (int m = 0; m < 4; m++)
#pragma unroll
      for (int n = 0; n < 4; n++) {
        int cl = wc * 64 + n * 16 + l15;      // d-local
        float bvv = bvf[n0v + cl];
#pragma unroll
        for (int r = 0; r < 4; r++) {
          int rl = wr * 64 + m * 16 + l4 * 4 + r;    // s-local
          T[cl * 136 + rl] = f2h(acc[m][n][r] + bvv);
        }
      }
    __syncthreads();
    int bidx = m0 >> 11, s0 = m0 & 2047;
#pragma unroll
    for (int i = 0; i < 8; i++) {
      int d = w * 32 + i * 4 + (lane >> 4);
      int ch = lane & 15;
      u16x8 v = *(const u16x8*)(T + d * 136 + ch * 8);
      *(u16x8*)(vtp + ((size_t)bidx * 1024 + n0v + d) * 2048 + s0 + ch * 8) = v;
    }
  }
}

// ---- kernel 4: per-wave row softmax (4 same-width rows per block) ----
__global__ __launch_bounds__(256) void softmax_row(const unsigned short* __restrict__ sc,
                                                   unsigned short* __restrict__ pb) {
  int base = blockIdx.x * 4;
  int b = base >> 11, sl0 = base & 2047;
  int w = threadIdx.x >> 6, lane = threadIdx.x & 63;
  int sl = sl0 + w;
  int qt = sl >> 7;
  int Wspan = (qt + 1) << 7;
  size_t rb = (size_t)b * P_ELEMS + (size_t)16384 * (qt * (qt + 1) / 2) + (size_t)(sl & 127) * Wspan;
  const u16x8* src = (const u16x8*)(sc + rb);
  int nc = Wspan >> 3;
  bool h0 = lane < nc, h1 = lane + 64 < nc, h2 = lane + 128 < nc, h3 = lane + 192 < nc;
  float v0[8], v1[8], v2[8], v3[8];
  float mx = -1e30f;
  if (h0) { u16x8 r = src[lane];
#pragma unroll
    for (int j = 0; j < 8; j++) { v0[j] = h2f(r[j]); mx = fmaxf(mx, v0[j]); } }
  if (h1) { u16x8 r = src[lane + 64];
#pragma unroll
    for (int j = 0; j < 8; j++) { v1[j] = h2f(r[j]); mx = fmaxf(mx, v1[j]); } }
  if (h2) { u16x8 r = src[lane + 128];
#pragma unroll
    for (int j = 0; j < 8; j++) { v2[j] = h2f(r[j]); mx = fmaxf(mx, v2[j]); } }
  if (h3) { u16x8 r = src[lane + 192];
#pragma unroll
    for (int j = 0; j < 8; j++) { v3[j] = h2f(r[j]); mx = fmaxf(mx, v3[j]); } }
  for (int off = 1; off < 64; off <<= 1) mx = fmaxf(mx, __shfl_xor(mx, off, 64));
  float s = 0.f;
  if (h0) {
#pragma unroll
    for (int j = 0; j < 8; j++) { v0[j] = __expf(v0[j] - mx); s += v0[j]; } }
  if (h1) {
#pragma unroll
    for (int j = 0; j < 8; j++) { v1[j] = __expf(v1[j] - mx); s += v1[j]; } }
  if (h2) {
#pragma unroll
    for (int j = 0; j < 8; j++) { v2[j] = __expf(v2[j] - mx); s += v2[j]; } }
  if (h3) {
#pragma unroll
    for (int j = 0; j < 8; j++) { v3[j] = __expf(v3[j] - mx); s += v3[j]; } }
  for (int off = 1; off < 64; off <<= 1) s += __shfl_xor(s, off, 64);
  float inv = 1.f / s;
  u16x8* dst = (u16x8*)(pb + rb);
  if (h0) { u16x8 o;
#pragma unroll
    for (int j = 0; j < 8; j++) o[j] = f2h(v0[j] * inv);
    dst[lane] = o; }
  if (h1) { u16x8 o;
#pragma unroll
    for (int j = 0; j < 8; j++) o[j] = f2h(v1[j] * inv);
    dst[lane + 64] = o; }
  if (h2) { u16x8 o;
#pragma unroll
    for (int j = 0; j < 8; j++) o[j] = f2h(v2[j] * inv);
    dst[lane + 128] = o; }
  if (h3) { u16x8 o;
#pragma unroll
    for (int j = 0; j < 8; j++) o[j] = f2h(v3[j] * inv);
    dst[lane + 192] = o; }
}

// ---- kernel 5: O = P Vt — 512 blocks, z-conjugate balance, f32 bounce epilogue ----
__global__ __launch_bounds__(256) void pv_gemm(const unsigned short* __restrict__ pb,
                                               const unsigned short* __restrict__ vtp,
                                               float* __restrict__ outp) {
  __shared__ unsigned short lds[2][16384];
  int bx = blockIdx.x;
  int n0 = blockIdx.y * 128;
  int bz = blockIdx.z;
  int qt = (bz & 2) ? (15 - bx) : bx;
  int b = bz;
  int tid = threadIdx.x, lane = tid & 63, w = tid >> 6;
  int wr = w >> 1, wc = w & 1, l15 = lane & 15, l4 = lane >> 4;
  const unsigned short* gB = vtp + (size_t)b * 1024 * 2048 + (size_t)n0 * 2048;
  int Wspan = (qt + 1) << 7;
  const unsigned short* gA = pb + (size_t)b * P_ELEMS + (size_t)16384 * (qt * (qt + 1) / 2);
  float* O = outp + ((size_t)b * 2048 + qt * 128) * 1024;
  f32x4 acc[4][4] = {};
  gemm_core(gA, gB, Wspan, 2048, &lds[0][0], &lds[1][0], 2 * (qt + 1),
            w, lane, wr, wc, l15, l4, acc);
  float* Tf = (float*)&lds[0][0];            // 128x128 f32, float4-chunk swizzle
#pragma unroll
  for (int m = 0; m < 4; m++)
#pragma unroll
    for (int n = 0; n < 4; n++) {
      int cl = wc * 64 + n * 16 + l15;
#pragma unroll
      for (int r = 0; r < 4; r++) {
        int rl = wr * 64 + m * 16 + l4 * 4 + r;
        int cc = cl >> 2;
        int sw = (((cc ^ (rl & 7)) << 2) | (cl & 3));
        Tf[rl * 128 + sw] = acc[m][n][r];
      }
    }
  __syncthreads();
#pragma unroll
  for (int i = 0; i < 16; i++) {
    int idx = i * 256 + tid;
    int row = idx >> 5, ch = idx & 31;
    float4 val = *(const float4*)&Tf[row * 128 + ((ch ^ (row & 7)) << 2)];
    *(float4*)&O[(size_t)row * 1024 + n0 + ch * 4] = val;
  }
}

extern "C" void kernel_launch(void* const* d_in, const int* in_sizes, int n_in,
                              void* d_out, int out_size, void* d_ws, size_t ws_size,
                              hipStream_t stream) {
  const float* x  = (const float*)d_in[0];
  const float* Wq = (const float*)d_in[1];
  const float* bq = (const float*)d_in[2];
  const float* Wk = (const float*)d_in[3];
  const float* bk = (const float*)d_in[4];
  const float* Wv = (const float*)d_in[5];
  const float* bv = (const float*)d_in[6];
  float* out = (float*)d_out;

  unsigned short* ws  = (unsigned short*)d_ws;
  unsigned short* wt  = ws;                          // 3,145,728 ushorts
  unsigned short* Qp  = ws + 3145728;                // 8,388,608
  unsigned short* Kp  = ws + 11534336;               // 8,388,608
  unsigned short* vtp = ws + 19922944;               // 8,388,608 (V^T [b][d][s])
  unsigned short* sc  = ws + 28311552;               // 4*P_ELEMS f16 scores
  unsigned short* pb  = ws + 37224448;               // 4*P_ELEMS f16 P
  unsigned short* xb  = (unsigned short*)d_out;      // x f16 scratch (overwritten by pv)

  cvt_fused<<<7168, 256, 0, stream>>>(x, Wq, Wk, Wv, xb, wt);
  qkv_gemm<<<dim3(64, 16), 256, 0, stream>>>(xb, wt, bq, bk, Qp, Kp);
  scores_v<<<1024, 256, 0, stream>>>(Qp, Kp, xb, wt, bv, sc, vtp);
  softmax_row<<<2048, 256, 0, stream>>>(sc, pb);
  pv_gemm<<<dim3(16, 8, 4), 256, 0, stream>>>(pb, vtp, out);
}